// Round 6
// baseline (1363.324 us; speedup 1.0000x reference)
//
#include <hip/hip_runtime.h>
#include <hip/hip_bf16.h>

typedef unsigned short u16;
typedef __attribute__((ext_vector_type(8))) short bf16x8;
typedef __attribute__((ext_vector_type(4))) float f32x4;

#define N_NODES 50000
#define EDGES 500000
#define NWAVES 3125   // node waves per type (50000/16)
#define NBLK 782      // ceil(NWAVES/4)

__device__ __forceinline__ u16 f2bf(float f) {
  return __builtin_bit_cast(u16, __float2bfloat16(f));
}
__device__ __forceinline__ float bf2f(u16 u) {
  return __builtin_bit_cast(float, ((unsigned)u) << 16);
}
__device__ __forceinline__ float bfe(bf16x8 v, int j) {
  return bf2f((u16)v[j]);
}

// ---------------------------------------------------------------------------
// weights -> bf16 tables (9 x 128x128 row-major)
// 0 Wp, 1 Wc, 2 W1a, 3 W1b, 4 W1c, 5 Wrel_ab, 6 Wroot_ab, 7 Wrel_ba, 8 Wroot_ba
// ---------------------------------------------------------------------------
__global__ __launch_bounds__(256) void prep_weights(
    const float* __restrict__ Wp, const float* __restrict__ Wc,
    const float* __restrict__ W1,
    const float* __restrict__ Wrel_ab, const float* __restrict__ Wroot_ab,
    const float* __restrict__ Wrel_ba, const float* __restrict__ Wroot_ba,
    u16* __restrict__ out)
{
  int tid = blockIdx.x * 256 + threadIdx.x;  // 9*16384
  int m = tid >> 14;
  int idx = tid & 16383;
  int r = idx >> 7;
  int c = idx & 127;
  float val;
  switch (m) {
    case 0: val = Wp[r * 128 + c]; break;
    case 1: val = Wc[r * 128 + c]; break;
    case 2: val = W1[r * 384 + c]; break;
    case 3: val = W1[r * 384 + 128 + c]; break;
    case 4: val = W1[r * 384 + 256 + c]; break;
    case 5: val = Wrel_ab[r * 128 + c]; break;
    case 6: val = Wroot_ab[r * 128 + c]; break;
    case 7: val = Wrel_ba[r * 128 + c]; break;
    default: val = Wroot_ba[r * 128 + c]; break;
  }
  out[tid] = f2bf(val);
}

// ---------------------------------------------------------------------------
// x -> bf16 tables (8 elems/thread) + dst histogram for both edge types
// ---------------------------------------------------------------------------
__global__ __launch_bounds__(256) void cast_x_hist(
    const float* __restrict__ xa, const float* __restrict__ xb,
    u16* __restrict__ oa, u16* __restrict__ ob,
    const int* __restrict__ ei_ab, const int* __restrict__ ei_ba,
    int* __restrict__ cnt)   // [2][50000], pre-zeroed
{
  int t = blockIdx.x * 256 + threadIdx.x;    // 1,600,000 threads
  const int HALF = (N_NODES * 128) / 8;      // 800,000
  const float* src;
  u16* dst;
  int idx;
  if (t < HALF) { src = xa; dst = oa; idx = t * 8; }
  else          { src = xb; dst = ob; idx = (t - HALF) * 8; }
  f32x4 a = *(const f32x4*)(src + idx);
  f32x4 b = *(const f32x4*)(src + idx + 4);
  bf16x8 o;
#pragma unroll
  for (int j = 0; j < 4; j++) {
    o[j]     = (short)f2bf(a[j]);
    o[j + 4] = (short)f2bf(b[j]);
  }
  *(bf16x8*)(dst + idx) = o;

  if (t < EDGES) {
    atomicAdd(&cnt[ei_ab[EDGES + t]], 1);
    atomicAdd(&cnt[N_NODES + ei_ba[EDGES + t]], 1);
  }
}

// ---------------------------------------------------------------------------
// exclusive scan of cnt[50000] -> cursor[50000], one block per type
// ---------------------------------------------------------------------------
__global__ __launch_bounds__(1024) void scan50k(
    const int* __restrict__ cnt, int* __restrict__ cursor)
{
  __shared__ int part[1024];
  const int* c = cnt + blockIdx.x * N_NODES;
  int* cur = cursor + blockIdx.x * N_NODES;
  int t = threadIdx.x;
  int lo = t * 49;
  int hi = lo + 49; if (hi > N_NODES) hi = N_NODES;
  if (lo > N_NODES) lo = N_NODES;
  int s = 0;
  for (int i = lo; i < hi; i++) s += c[i];
  part[t] = s;
  __syncthreads();
  for (int off = 1; off < 1024; off <<= 1) {
    int v = (t >= off) ? part[t - off] : 0;
    __syncthreads();
    part[t] += v;
    __syncthreads();
  }
  int base = (t == 0) ? 0 : part[t - 1];
  for (int i = lo; i < hi; i++) { cur[i] = base; base += c[i]; }
}

// ---------------------------------------------------------------------------
// scatter edges into dst-sorted order. After this, cursor[d] = segment END.
// ---------------------------------------------------------------------------
__global__ __launch_bounds__(256) void edge_sort(
    const int* __restrict__ ei_ab, const int* __restrict__ ei_ba,
    int* __restrict__ cursor,
    int2* __restrict__ sorted_ab, int2* __restrict__ sorted_ba)
{
  int t = blockIdx.x * 256 + threadIdx.x;   // >= 1,000,000
  if (t < EDGES) {
    int s = ei_ab[t], d = ei_ab[EDGES + t];
    int pos = atomicAdd(&cursor[d], 1);
    sorted_ab[pos] = make_int2(s, d);
  } else if (t < 2 * EDGES) {
    int tt = t - EDGES;
    int s = ei_ba[tt], d = ei_ba[EDGES + tt];
    int pos = atomicAdd(&cursor[N_NODES + d], 1);
    sorted_ba[pos] = make_int2(s, d);
  }
}

// ---------------------------------------------------------------------------
// Fused encoder, both node sets in one dispatch (grid 2*NBLK):
//   u = lrelu(x@Wp^T+bp) @ W1a^T + b1   (b1 folded in)
//   v = lrelu(x@Wc^T+bc) @ W1b^T
// ---------------------------------------------------------------------------
__global__ __launch_bounds__(256) void encoder2(
    const u16* __restrict__ xa_bf, const u16* __restrict__ xb_bf,
    const u16* __restrict__ Wp_b, const float* __restrict__ bp,
    const u16* __restrict__ Wc_b, const float* __restrict__ bc,
    const u16* __restrict__ W1a_b, const float* __restrict__ b1,
    const u16* __restrict__ W1b_b,
    u16* __restrict__ u_a, u16* __restrict__ v_a,
    u16* __restrict__ u_b, u16* __restrict__ v_b)
{
  __shared__ u16 tile[4][2176];   // 16 x pitch 136 bf16, per wave
  int widx = threadIdx.x >> 6;
  int w = blockIdx.x * 4 + widx;
  int type = (w >= NBLK * 4) ? 1 : 0;
  int nw = w - type * NBLK * 4;
  if (nw >= NWAVES) nw = NWAVES - 1;     // clamp (dup work; per-wave tile, safe)
  const u16* xbf = type ? xb_bf : xa_bf;
  u16* u_out = type ? u_b : u_a;
  u16* v_out = type ? v_b : v_a;
  int row0 = nw * 16;
  int lane = threadIdx.x & 63;
  int col = lane & 15;
  int quad = lane >> 4;
  u16* tl = tile[widx];

  bf16x8 af[4];
#pragma unroll
  for (int ks = 0; ks < 4; ks++)
    af[ks] = *(const bf16x8*)(xbf + (size_t)(row0 + col) * 128 + ks * 32 + quad * 8);

  f32x4 zero = {0.f, 0.f, 0.f, 0.f};

  for (int chain = 0; chain < 2; chain++) {
    const u16* Wenc = chain ? Wc_b : Wp_b;
    const float* benc = chain ? bc : bp;
    const u16* Wmix = chain ? W1b_b : W1a_b;
    const float* bmix = chain ? nullptr : b1;
    u16* outp = chain ? v_out : u_out;

    f32x4 acc[8];
#pragma unroll
    for (int nt = 0; nt < 8; nt++) acc[nt] = zero;
#pragma unroll
    for (int ks = 0; ks < 4; ks++) {
      const u16* wp = Wenc + col * 128 + ks * 32 + quad * 8;
#pragma unroll
      for (int nt = 0; nt < 8; nt++) {
        bf16x8 bf = *(const bf16x8*)(wp + nt * 2048);
        acc[nt] = __builtin_amdgcn_mfma_f32_16x16x32_bf16(af[ks], bf, acc[nt], 0, 0, 0);
      }
    }
#pragma unroll
    for (int nt = 0; nt < 8; nt++) {
      float be = benc[nt * 16 + col];
#pragma unroll
      for (int r = 0; r < 4; r++) {
        float v = acc[nt][r] + be;
        v = v > 0.f ? v : 0.01f * v;
        tl[(quad * 4 + r) * 136 + nt * 16 + col] = f2bf(v);
      }
    }
    bf16x8 a2[4];
#pragma unroll
    for (int ks = 0; ks < 4; ks++)
      a2[ks] = *(const bf16x8*)&tl[col * 136 + ks * 32 + quad * 8];

    f32x4 acc2[8];
#pragma unroll
    for (int nt = 0; nt < 8; nt++) acc2[nt] = zero;
#pragma unroll
    for (int ks = 0; ks < 4; ks++) {
      const u16* wp = Wmix + col * 128 + ks * 32 + quad * 8;
#pragma unroll
      for (int nt = 0; nt < 8; nt++) {
        bf16x8 bf = *(const bf16x8*)(wp + nt * 2048);
        acc2[nt] = __builtin_amdgcn_mfma_f32_16x16x32_bf16(a2[ks], bf, acc2[nt], 0, 0, 0);
      }
    }
#pragma unroll
    for (int nt = 0; nt < 8; nt++) {
      float bm = bmix ? bmix[nt * 16 + col] : 0.f;
#pragma unroll
      for (int r = 0; r < 4; r++)
        outp[(size_t)(row0 + quad * 4 + r) * 128 + nt * 16 + col] = f2bf(acc2[nt][r] + bm);
    }
  }
}

// ---------------------------------------------------------------------------
// Mega edge kernel: wave owns 16 dst nodes; iterates its dst-sorted CSR
// segment in 16-edge batches; accumulates msg = sum w_e x_src in per-wave
// LDS fp32 tile (ds atomics, no global atomics); then fused output GEMM:
// out = msg@Wrel^T + x@Wroot^T + brel + broot.
// ---------------------------------------------------------------------------
__global__ __launch_bounds__(256) void edge_mega(
    const u16* __restrict__ xa_bf, const u16* __restrict__ xb_bf,
    const int2* __restrict__ sorted_ab, const int2* __restrict__ sorted_ba,
    const int* __restrict__ cursor,     // post-sort: segment ends
    const u16* __restrict__ W1c,
    const u16* __restrict__ u_a, const u16* __restrict__ v_a,
    const u16* __restrict__ u_b, const u16* __restrict__ v_b,
    const float* __restrict__ W2, const float* __restrict__ b2p,
    const u16* __restrict__ Wrelab, const u16* __restrict__ Wrootab,
    const float* __restrict__ brel_ab, const float* __restrict__ broot_ab,
    const u16* __restrict__ Wrelba, const u16* __restrict__ Wrootba,
    const float* __restrict__ brel_ba, const float* __restrict__ broot_ba,
    float* __restrict__ out_a, float* __restrict__ out_b)
{
  __shared__ u16 tls[4][2176];      // 16 x pitch 136 bf16, per wave
  __shared__ float msga[4][2112];   // 16 x pitch 132 fp32, per wave
  int widx = threadIdx.x >> 6;
  int w = blockIdx.x * 4 + widx;    // 0..6251
  if (w >= 2 * NWAVES) w = 2 * NWAVES - 1;   // dup work, benign
  int type = (w >= NWAVES) ? 1 : 0;
  int g = w - type * NWAVES;
  int n0 = g * 16;

  const u16* xs = type ? xb_bf : xa_bf;          // src table (random)
  const u16* xd = type ? xa_bf : xb_bf;          // owned/dst table (hot)
  const int2* se = type ? sorted_ba : sorted_ab;
  const int* cur = cursor + type * N_NODES;
  const u16* uT = type ? u_b : u_a;
  const u16* vT = type ? v_a : v_b;
  const u16* Wrel  = type ? Wrelba : Wrelab;
  const u16* Wroot = type ? Wrootba : Wrootab;
  const float* brel  = type ? brel_ba : brel_ab;
  const float* broot = type ? broot_ba : broot_ab;
  float* outp = type ? out_a : out_b;

  int start = (n0 == 0) ? 0 : cur[n0 - 1];
  int end = cur[n0 + 15];

  int lane = threadIdx.x & 63;
  int col = lane & 15;
  int quad = lane >> 4;
  u16* tl = tls[widx];
  float* macc = msga[widx];

  for (int i = lane; i < 2112; i += 64) macc[i] = 0.f;

  // preload owned x rows (A-frag layout) for the final GEMM
  bf16x8 ax[4];
#pragma unroll
  for (int ks = 0; ks < 4; ks++)
    ax[ks] = *(const bf16x8*)(xd + (size_t)(n0 + col) * 128 + ks * 32 + quad * 8);

  float b2 = b2p[0];
  f32x4 zero = {0.f, 0.f, 0.f, 0.f};

  for (int base = start; base < end; base += 16) {
    // ---- phase 1: MFMA t = |x_s - x_d| @ W1c^T for 16 edges ----
    int em = base + col;
    if (em >= end) em = end - 1;
    int2 pe = se[em];

    bf16x8 af[4], df[4];
#pragma unroll
    for (int ks = 0; ks < 4; ks++) {
      af[ks] = *(const bf16x8*)(xs + (size_t)pe.x * 128 + ks * 32 + quad * 8);
      bf16x8 d8 = *(const bf16x8*)(xd + (size_t)pe.y * 128 + ks * 32 + quad * 8);
#pragma unroll
      for (int j = 0; j < 8; j++)
        df[ks][j] = (short)f2bf(__builtin_fabsf(bfe(af[ks], j) - bfe(d8, j)));
    }

    f32x4 acc[8];
#pragma unroll
    for (int nt = 0; nt < 8; nt++) acc[nt] = zero;
#pragma unroll
    for (int ks = 0; ks < 4; ks++) {
      const u16* wp = W1c + col * 128 + ks * 32 + quad * 8;
#pragma unroll
      for (int nt = 0; nt < 8; nt++) {
        bf16x8 bf = *(const bf16x8*)(wp + nt * 2048);
        acc[nt] = __builtin_amdgcn_mfma_f32_16x16x32_bf16(df[ks], bf, acc[nt], 0, 0, 0);
      }
    }
#pragma unroll
    for (int nt = 0; nt < 8; nt++)
#pragma unroll
      for (int r = 0; r < 4; r++)
        tl[(quad * 4 + r) * 136 + nt * 16 + col] = f2bf(acc[nt][r]);

    // ---- epilogue: w per edge (lane = edge lane>>2, strip (lane&3)*32) ----
    int e2 = base + (lane >> 2);
    bool evalid = e2 < end;
    int2 q = se[evalid ? e2 : end - 1];
    int c0 = (lane & 3) * 32;
    const u16* trow = &tl[(lane >> 2) * 136 + c0];
    const u16* urow = uT + (size_t)q.x * 128 + c0;
    const u16* vrow = vT + (size_t)q.y * 128 + c0;

    float p = 0.f;
#pragma unroll
    for (int k = 0; k < 4; k++) {
      bf16x8 tt = *(const bf16x8*)(trow + k * 8);
      bf16x8 uu = *(const bf16x8*)(urow + k * 8);
      bf16x8 vv = *(const bf16x8*)(vrow + k * 8);
      f32x4 w0 = *(const f32x4*)(W2 + c0 + k * 8);
      f32x4 w1 = *(const f32x4*)(W2 + c0 + k * 8 + 4);
#pragma unroll
      for (int j = 0; j < 4; j++) {
        float q0 = bfe(tt, j) + bfe(uu, j) + bfe(vv, j);
        if (q0 > 0.f) p += q0 * w0[j];
        float q1 = bfe(tt, j + 4) + bfe(uu, j + 4) + bfe(vv, j + 4);
        if (q1 > 0.f) p += q1 * w1[j];
      }
    }
    p += __shfl_xor(p, 1, 64);
    p += __shfl_xor(p, 2, 64);
    float wgt = evalid ? 1.f / (1.f + __expf(-(p + b2))) : 0.f;
    int dloc = q.y - n0;   // 0..15

    // xs frags -> tl (t reads above are in-wave ordered before this)
#pragma unroll
    for (int ks = 0; ks < 4; ks++)
      *(bf16x8*)&tl[col * 136 + ks * 32 + quad * 8] = af[ks];

    // ---- scatter into per-wave LDS fp32 accumulator ----
#pragma unroll
    for (int r = 0; r < 4; r++) {
      int src_lane = (quad * 4 + r) * 4;
      float wr = __shfl(wgt, src_lane, 64);
      int ldr = __shfl(dloc, src_lane, 64);
      const u16* xrow = &tl[(quad * 4 + r) * 136];
      float* mrow = &macc[ldr * 132];
#pragma unroll
      for (int nt = 0; nt < 4; nt++) {
        int c = nt * 32 + col * 2;
        unsigned xv = *(const unsigned*)(xrow + c);
        atomicAdd(&mrow[c],     wr * bf2f((u16)(xv & 0xffff)));
        atomicAdd(&mrow[c + 1], wr * bf2f((u16)(xv >> 16)));
      }
    }
  }

  // ---- final fused GEMM: out = msg@Wrel^T + x@Wroot^T + biases ----
  bf16x8 am[4];
#pragma unroll
  for (int ks = 0; ks < 4; ks++) {
    f32x4 a0 = *(const f32x4*)&macc[col * 132 + ks * 32 + quad * 8];
    f32x4 a1 = *(const f32x4*)&macc[col * 132 + ks * 32 + quad * 8 + 4];
#pragma unroll
    for (int j = 0; j < 4; j++) {
      am[ks][j]     = (short)f2bf(a0[j]);
      am[ks][j + 4] = (short)f2bf(a1[j]);
    }
  }

  f32x4 acc2[8];
#pragma unroll
  for (int nt = 0; nt < 8; nt++) acc2[nt] = zero;
#pragma unroll
  for (int ks = 0; ks < 4; ks++) {
    const u16* wp1 = Wrel + col * 128 + ks * 32 + quad * 8;
    const u16* wp2 = Wroot + col * 128 + ks * 32 + quad * 8;
#pragma unroll
    for (int nt = 0; nt < 8; nt++) {
      bf16x8 b1f = *(const bf16x8*)(wp1 + nt * 2048);
      acc2[nt] = __builtin_amdgcn_mfma_f32_16x16x32_bf16(am[ks], b1f, acc2[nt], 0, 0, 0);
      bf16x8 b2f = *(const bf16x8*)(wp2 + nt * 2048);
      acc2[nt] = __builtin_amdgcn_mfma_f32_16x16x32_bf16(ax[ks], b2f, acc2[nt], 0, 0, 0);
    }
  }
#pragma unroll
  for (int nt = 0; nt < 8; nt++) {
    int c = nt * 16 + col;
    float b = brel[c] + broot[c];
#pragma unroll
    for (int r = 0; r < 4; r++)
      outp[(size_t)(n0 + quad * 4 + r) * 128 + c] = acc2[nt][r] + b;
  }
}

// ---------------------------------------------------------------------------
extern "C" void kernel_launch(void* const* d_in, const int* in_sizes, int n_in,
                              void* d_out, int out_size, void* d_ws, size_t ws_size,
                              hipStream_t stream) {
  const float* x_a      = (const float*)d_in[0];
  const float* x_b      = (const float*)d_in[1];
  const float* Wp       = (const float*)d_in[2];
  const float* bp       = (const float*)d_in[3];
  const float* Wc       = (const float*)d_in[4];
  const float* bc       = (const float*)d_in[5];
  const float* W1       = (const float*)d_in[6];
  const float* b1       = (const float*)d_in[7];
  const float* W2       = (const float*)d_in[8];
  const float* b2       = (const float*)d_in[9];
  const float* Wrel_ab  = (const float*)d_in[10];
  const float* brel_ab  = (const float*)d_in[11];
  const float* Wroot_ab = (const float*)d_in[12];
  const float* broot_ab = (const float*)d_in[13];
  const float* Wrel_ba  = (const float*)d_in[14];
  const float* brel_ba  = (const float*)d_in[15];
  const float* Wroot_ba = (const float*)d_in[16];
  const float* broot_ba = (const float*)d_in[17];
  const int*   ei_ab    = (const int*)d_in[18];
  const int*   ei_ba    = (const int*)d_in[19];

  char* ws = (char*)d_ws;
  u16* Wb        = (u16*)ws;               // 9*16384*2 B
  u16* Wp_b      = Wb + 0 * 16384;
  u16* Wc_b      = Wb + 1 * 16384;
  u16* W1a_b     = Wb + 2 * 16384;
  u16* W1b_b     = Wb + 3 * 16384;
  u16* W1c_b     = Wb + 4 * 16384;
  u16* Wrelab_b  = Wb + 5 * 16384;
  u16* Wrootab_b = Wb + 6 * 16384;
  u16* Wrelba_b  = Wb + 7 * 16384;
  u16* Wrootba_b = Wb + 8 * 16384;

  u16* xa_bf   = (u16*)(ws + 1048576);     // 12.8 MB each
  u16* xb_bf   = (u16*)(ws + 13848576);
  u16* u_a     = (u16*)(ws + 26648576);
  u16* v_a     = (u16*)(ws + 39448576);
  u16* u_b     = (u16*)(ws + 52248576);
  u16* v_b     = (u16*)(ws + 65048576);
  int* cnt     = (int*)(ws + 77848576);    // [2][50000] = 400 KB
  int* cursor  = (int*)(ws + 78248576);    // [2][50000]
  int2* sorted_ab = (int2*)(ws + 78648576);  // 4 MB
  int2* sorted_ba = (int2*)(ws + 82648576);  // 4 MB

  float* out_a = (float*)d_out;
  float* out_b = out_a + (size_t)N_NODES * 128;

  hipMemsetAsync(cnt, 0, 2 * N_NODES * sizeof(int), stream);

  prep_weights<<<576, 256, 0, stream>>>(Wp, Wc, W1, Wrel_ab, Wroot_ab,
                                        Wrel_ba, Wroot_ba, Wb);
  cast_x_hist<<<6250, 256, 0, stream>>>(x_a, x_b, xa_bf, xb_bf, ei_ab, ei_ba, cnt);
  scan50k<<<2, 1024, 0, stream>>>(cnt, cursor);
  edge_sort<<<3907, 256, 0, stream>>>(ei_ab, ei_ba, cursor, sorted_ab, sorted_ba);

  encoder2<<<2 * NBLK, 256, 0, stream>>>(xa_bf, xb_bf, Wp_b, bp, Wc_b, bc,
                                         W1a_b, b1, W1b_b, u_a, v_a, u_b, v_b);

  edge_mega<<<1563, 256, 0, stream>>>(xa_bf, xb_bf, sorted_ab, sorted_ba, cursor,
                                      W1c_b, u_a, v_a, u_b, v_b, W2, b2,
                                      Wrelab_b, Wrootab_b, brel_ab, broot_ab,
                                      Wrelba_b, Wrootba_b, brel_ba, broot_ba,
                                      out_a, out_b);
}